// Round 1
// baseline (952.454 us; speedup 1.0000x reference)
//
#include <hip/hip_runtime.h>
#include <hip/hip_bf16.h>

#define ROWS 18
#define HID 1024

__device__ __forceinline__ float dot4(float4 a, float4 b){
  return fmaf(a.x,b.x, fmaf(a.y,b.y, fmaf(a.z,b.z, a.w*b.w)));
}

// Skinny GEMM: out[18][C] (+bias, +rms-scale, or atomic-accumulate) = act[18][K] @ W[C][K]^T
// Decomposition: block = 4 waves; wave = G groups x (64/G) lanes; each group owns NC=4 columns.
// blockIdx.x -> column block, blockIdx.y -> K-split (S). Activations staged in LDS (f32),
// in passes of PK<=512 columns of K. RMS folded into epilogue (scale per row).
template<int K, int S, int G, int NC, int ACT, int CSTR, bool RMS, bool BIAS, bool ATOMIC>
__global__ __launch_bounds__(256)
void gemm18(const float* __restrict__ W, const float* __restrict__ act,
            const float* __restrict__ bias, float* __restrict__ out)
{
  constexpr int L   = 64 / G;
  constexpr int KB  = K / S;            // K range per block
  constexpr int PK  = (KB <= 512) ? KB : 512;
  constexpr int NP  = KB / PK;          // staging passes
  constexpr int CHUNK = 4 * L;          // K elems per chunk per group
  constexpr int NCH = PK / CHUNK;       // chunks per pass
  constexpr int CPB = 4 * G * NC;       // columns per block

  __shared__ float s_act[ROWS][PK];
  __shared__ float s_red[4 * G * NC * ROWS];
  __shared__ float s_scale[ROWS];

  const int tid  = threadIdx.x;
  const int w    = tid >> 6;
  const int lane = tid & 63;
  const int g    = (G == 1) ? 0 : (lane / L);
  const int l    = (G == 1) ? lane : (lane % L);
  const int cb   = blockIdx.x * CPB + (w * G + g) * NC;
  const int k0   = blockIdx.y * KB;

  float acc[NC][ROWS];
  #pragma unroll
  for (int i = 0; i < NC; i++)
    #pragma unroll
    for (int r = 0; r < ROWS; r++) acc[i][r] = 0.f;

  float rs[5];
  #pragma unroll
  for (int t = 0; t < 5; t++) rs[t] = 0.f;

  for (int p = 0; p < NP; p++) {
    __syncthreads();
    // ---- stage activations (f32) into LDS, coalesced float4 ----
    constexpr int N4 = ROWS * PK / 4;
    for (int t4 = tid; t4 < N4; t4 += 256) {
      const int r  = t4 / (PK / 4);
      const int k4 = (t4 % (PK / 4)) * 4;
      const int kg = k0 + p * PK + k4;
      float4 v;
      if (ACT == 0) {
        v = *(const float4*)&act[(size_t)r * K + kg];
      } else {
        // down-proj input: silu(g)*u from gu[18][8192]
        float4 gv = *(const float4*)&act[(size_t)r * 8192 + kg];
        float4 uv = *(const float4*)&act[(size_t)r * 8192 + 4096 + kg];
        v.x = gv.x / (1.f + __expf(-gv.x)) * uv.x;
        v.y = gv.y / (1.f + __expf(-gv.y)) * uv.y;
        v.z = gv.z / (1.f + __expf(-gv.z)) * uv.z;
        v.w = gv.w / (1.f + __expf(-gv.w)) * uv.w;
      }
      *(float4*)&s_act[r][k4] = v;
    }
    __syncthreads();

    // ---- rms partial row-sumsq (read from LDS; wave w owns rows w, w+4, ...) ----
    if (RMS) {
      #pragma unroll
      for (int t = 0; t < 5; t++) {
        const int r = w + 4 * t;
        if (r < ROWS) {
          float ss = 0.f;
          for (int kk = 4 * lane; kk < PK; kk += 256) {
            float4 a = *(const float4*)&s_act[r][kk];
            ss += dot4(a, a);
          }
          rs[t] += ss;
        }
      }
    }

    // ---- main FMA loop: stream weights, MAC against all 18 rows ----
    #pragma unroll
    for (int ch = 0; ch < NCH; ch++) {
      const int kk = ch * CHUNK + 4 * l;
      float4 wv[NC];
      #pragma unroll
      for (int i = 0; i < NC; i++)
        wv[i] = *(const float4*)&W[(size_t)(cb + i) * K + k0 + p * PK + kk];
      #pragma unroll
      for (int r = 0; r < ROWS; r++) {
        float4 a = *(const float4*)&s_act[r][kk];
        #pragma unroll
        for (int i = 0; i < NC; i++)
          acc[i][r] = fmaf(wv[i].x, a.x, fmaf(wv[i].y, a.y,
                      fmaf(wv[i].z, a.z, fmaf(wv[i].w, a.w, acc[i][r]))));
      }
    }
  }

  // ---- finalize rms scales ----
  if (RMS) {
    #pragma unroll
    for (int t = 0; t < 5; t++) {
      const int r = w + 4 * t;
      if (r < ROWS) {
        float ss = rs[t];
        #pragma unroll
        for (int m = 32; m >= 1; m >>= 1) ss += __shfl_xor(ss, m);
        if (lane == 0) s_scale[r] = rsqrtf(ss);
      }
    }
  }

  // ---- in-group butterfly reduce, park in LDS ----
  #pragma unroll
  for (int i = 0; i < NC; i++)
    #pragma unroll
    for (int r = 0; r < ROWS; r++) {
      float v = acc[i][r];
      #pragma unroll
      for (int m = L / 2; m >= 1; m >>= 1) v += __shfl_xor(v, m);
      if (l == 0) s_red[((w * G + g) * NC + i) * ROWS + r] = v;
    }
  __syncthreads();

  // ---- epilogue ----
  constexpr int TOT = 4 * G * NC * ROWS;
  for (int t = tid; t < TOT; t += 256) {
    const int r    = t % ROWS;
    const int rest = t / ROWS;
    const int c    = blockIdx.x * CPB + rest;
    float v = s_red[rest * ROWS + r];
    if (RMS)  v *= s_scale[r];
    if (BIAS) v += bias[c];
    if (ATOMIC) atomicAdd(&out[(size_t)r * CSTR + c], v);
    else        out[(size_t)r * CSTR + c] = v;
  }
}

// Build hs[18][1024]: rows p=0 (dit_hidden+t | t), p=1..4 feat_cond, p=5..8 in_proj(random)
__global__ __launch_bounds__(256)
void prep_kernel(const int* __restrict__ step, const float* __restrict__ random_,
                 const float* __restrict__ dit_hidden, const float* __restrict__ feat_cond,
                 const float* __restrict__ t_emb, const float* __restrict__ in_w,
                 const float* __restrict__ in_b, float* __restrict__ hs)
{
  const int c = blockIdx.x * 256 + threadIdx.x;
  const int st = step[0];
  const float tv = t_emb[(size_t)st * HID + c];
  hs[0 * HID + c] = dit_hidden[c] + tv;
  hs[9 * HID + c] = tv;
  #pragma unroll
  for (int p = 0; p < 4; p++) {
    hs[(1 + p) * HID + c]     = feat_cond[(0 * 4 + p) * HID + c];
    hs[(9 + 1 + p) * HID + c] = feat_cond[(1 * 4 + p) * HID + c];
  }
  #pragma unroll
  for (int p = 0; p < 4; p++) {
    float a = in_b[c];
    #pragma unroll
    for (int q4 = 0; q4 < 16; q4++) {
      float4 wv = *(const float4*)&in_w[c * 64 + q4 * 4];
      float4 rv = *(const float4*)&random_[p * 64 + q4 * 4];
      a += dot4(wv, rv);
    }
    hs[(5 + p) * HID + c]     = a;
    hs[(9 + 5 + p) * HID + c] = a;
  }
}

// One wave per (batch, head): RoPE + scores + softmax + PV. lane = head_dim d.
__global__ __launch_bounds__(64)
void attn_kernel(const float* __restrict__ qkv, float* __restrict__ attn_out)
{
  const int bh = blockIdx.x;
  const int b = bh >> 4, h = bh & 15;
  const int d = threadIdx.x;
  const float* base = qkv + (size_t)b * 9 * 3072;
  float q[9], k[9], v[9];
  #pragma unroll
  for (int i = 0; i < 9; i++) {
    q[i] = base[i * 3072 + h * 64 + d];
    k[i] = base[i * 3072 + (16 + h) * 64 + d];
    v[i] = base[i * 3072 + (32 + h) * 64 + d];
  }
  // RoPE: partner element is exactly d^32; sin sign: -sin for d<32, +sin for d>=32
  const int j = d & 31;
  const float inv = powf(10000.f, -(float)j * (1.f / 32.f));
  #pragma unroll
  for (int i = 0; i < 9; i++) {
    const float ang = (float)i * inv;
    float sn, cs;
    sincosf(ang, &sn, &cs);
    const float sgn = (d < 32) ? -sn : sn;
    const float rq = __shfl_xor(q[i], 32);
    const float rk = __shfl_xor(k[i], 32);
    q[i] = q[i] * cs + rq * sgn;
    k[i] = k[i] * cs + rk * sgn;
  }
  float* obase = attn_out + (size_t)b * 9 * HID + h * 64 + d;
  for (int i = 0; i < 9; i++) {
    float sc[9];
    #pragma unroll
    for (int jj = 0; jj < 9; jj++) {
      float p = q[i] * k[jj];
      #pragma unroll
      for (int m = 32; m >= 1; m >>= 1) p += __shfl_xor(p, m);
      sc[jj] = p;   // all lanes hold full score
    }
    float mx = sc[0];
    #pragma unroll
    for (int jj = 1; jj < 9; jj++) mx = fmaxf(mx, sc[jj]);
    float den = 0.f;
    #pragma unroll
    for (int jj = 0; jj < 9; jj++) { sc[jj] = __expf(sc[jj] - mx); den += sc[jj]; }
    float o = 0.f;
    #pragma unroll
    for (int jj = 0; jj < 9; jj++) o += sc[jj] * v[jj];
    obase[i * HID] = o / den;
  }
}

// out_tmp[8][64] = rms(hs rows {5..8}x{b0,b1}) @ out_proj_w^T + b  (block per column)
__global__ __launch_bounds__(256)
void outproj_kernel(const float* __restrict__ hs, const float* __restrict__ W,
                    const float* __restrict__ bias, float* __restrict__ out_tmp)
{
  const int c = blockIdx.x, t = threadIdx.x;
  const int w = t >> 6, lane = t & 63;
  const float4 w4 = *(const float4*)&W[(size_t)c * HID + t * 4];
  __shared__ float la[8][4], ls[8][4];
  #pragma unroll
  for (int r8 = 0; r8 < 8; r8++) {
    const int row = (r8 >> 2) * 9 + 5 + (r8 & 3);
    const float4 h4 = *(const float4*)&hs[(size_t)row * HID + t * 4];
    float a = dot4(w4, h4), s = dot4(h4, h4);
    #pragma unroll
    for (int m = 32; m >= 1; m >>= 1) { a += __shfl_xor(a, m); s += __shfl_xor(s, m); }
    if (lane == 0) { la[r8][w] = a; ls[r8][w] = s; }
  }
  __syncthreads();
  if (t < 8) {
    const float a = la[t][0] + la[t][1] + la[t][2] + la[t][3];
    const float s = ls[t][0] + ls[t][1] + ls[t][2] + ls[t][3];
    out_tmp[t * 64 + c] = a * rsqrtf(s) + bias[c];
  }
}

// CFG combine + residual add -> d_out[256]
__global__ __launch_bounds__(256)
void combine_kernel(const float* __restrict__ out_tmp, const float* __restrict__ random_,
                    const float* __restrict__ cfg, const float* __restrict__ cfgm,
                    const float* __restrict__ dt, const int* __restrict__ step,
                    float* __restrict__ dout)
{
  const int t = threadIdx.x;
  const int w = t >> 6, lane = t & 63;
  const float pos = out_tmp[t], neg = out_tmp[256 + t];
  float d = pos * neg, s = neg * neg;
  #pragma unroll
  for (int m = 32; m >= 1; m >>= 1) { d += __shfl_xor(d, m); s += __shfl_xor(s, m); }
  __shared__ float ld[4], lsq[4];
  if (lane == 0) { ld[w] = d; lsq[w] = s; }
  __syncthreads();
  const float dot = ld[0] + ld[1] + ld[2] + ld[3];
  const float sq  = lsq[0] + lsq[1] + lsq[2] + lsq[3];
  const float guided = cfg[0] * pos + cfgm[0] * (dot / sq) * neg;
  dout[t] = random_[t] + guided * dt[step[0]];
}

extern "C" void kernel_launch(void* const* d_in, const int* in_sizes, int n_in,
                              void* d_out, int out_size, void* d_ws, size_t ws_size,
                              hipStream_t stream)
{
  const int*   step   = (const int*)  d_in[0];
  const float* random_= (const float*)d_in[1];
  const float* dit_h  = (const float*)d_in[2];
  const float* feat   = (const float*)d_in[3];
  const float* cfg    = (const float*)d_in[4];
  const float* cfgm   = (const float*)d_in[5];
  const float* t_emb  = (const float*)d_in[6];
  const float* dt     = (const float*)d_in[7];
  const float* in_w   = (const float*)d_in[8];
  const float* in_b   = (const float*)d_in[9];
  const float* qkv_w  = (const float*)d_in[10];
  const float* qkv_b  = (const float*)d_in[11];
  const float* o_w    = (const float*)d_in[12];
  const float* gu_w   = (const float*)d_in[13];
  const float* dn_w   = (const float*)d_in[14];
  const float* op_w   = (const float*)d_in[15];
  const float* op_b   = (const float*)d_in[16];

  float* hs     = (float*)d_ws;          // 18*1024
  float* qkvb   = hs    + ROWS * HID;    // 18*3072
  float* attnb  = qkvb  + ROWS * 3072;   // 18*1024
  float* gub    = attnb + ROWS * HID;    // 18*8192
  float* outtmp = gub   + ROWS * 8192;   // 512

  prep_kernel<<<4, 256, 0, stream>>>(step, random_, dit_h, feat, t_emb, in_w, in_b, hs);

  for (int i = 0; i < 8; i++) {
    const float* qw = qkv_w + (size_t)i * 3072 * 1024;
    const float* qb = qkv_b + (size_t)i * 3072;
    const float* ow = o_w   + (size_t)i * 1024 * 1024;
    const float* gw = gu_w  + (size_t)i * 8192 * 1024;
    const float* dw = dn_w  + (size_t)i * 1024 * 4096;

    // QKV: C=3072 K=1024, rms+bias, 192 blocks
    gemm18<1024, 1, 1, 4, 0, 3072, true,  true,  false>
        <<<dim3(192, 1), 256, 0, stream>>>(qw, hs, qb, qkvb);
    attn_kernel<<<32, 64, 0, stream>>>(qkvb, attnb);
    // O: C=1024 K=1024, S=4 K-split, atomic residual-add into hs, 256 blocks
    gemm18<1024, 4, 1, 4, 0, 1024, false, false, true>
        <<<dim3(64, 4), 256, 0, stream>>>(ow, attnb, nullptr, hs);
    // gate_up: C=8192 K=1024, rms, 256 blocks
    gemm18<1024, 1, 2, 4, 0, 8192, true,  false, false>
        <<<dim3(256, 1), 256, 0, stream>>>(gw, hs, nullptr, gub);
    // down: C=1024 K=4096, silu-fused staging, S=4 K-split, atomic into hs, 256 blocks
    gemm18<4096, 4, 1, 4, 1, 1024, false, false, true>
        <<<dim3(64, 4), 256, 0, stream>>>(dw, gub, nullptr, hs);
  }

  outproj_kernel<<<64, 256, 0, stream>>>(hs, op_w, op_b, outtmp);
  combine_kernel<<<1, 256, 0, stream>>>(outtmp, random_, cfg, cfgm, dt, step, (float*)d_out);
}